// Round 2
// baseline (192.466 us; speedup 1.0000x reference)
//
#include <hip/hip_runtime.h>
#include <stdint.h>

typedef unsigned short u16;
typedef __attribute__((ext_vector_type(8))) __bf16 bf16x8;
typedef __attribute__((ext_vector_type(4))) float f32x4;
typedef __attribute__((ext_vector_type(4))) u16 u16x4;
typedef __attribute__((ext_vector_type(8))) u16 u16x8;

#define N_IMG 64
#define C_IN  64
#define HW_IN 3136   // 56*56
#define W_IN  56
#define C_OUT 128
#define OH    54
#define OW    54
#define SPI   2916   // 54*54
#define KTOT  576    // C_IN*9
#define M_TOTAL (N_IMG*SPI)   // 186624 = 128 * 1458

typedef __attribute__((address_space(3))) unsigned int lds_uint;
typedef __attribute__((address_space(1))) unsigned int gbl_uint;

__device__ __forceinline__ void load16_to_lds(const u16* g, u16* l) {
  // lane i of the wave writes LDS base + i*16 bytes; g is per-lane.
  __builtin_amdgcn_global_load_lds((const gbl_uint*)g, (lds_uint*)l, 16, 0, 0);
}

__device__ inline u16 f32_bf16_rne(float f) {
  unsigned u = __float_as_uint(f);
  u = (u + 0x7FFFu + ((u >> 16) & 1u)) >> 16;
  return (u16)u;
}

// Merged converter.
//  blockIdx.y <  N_IMG : xt[n][s][ci] (NHWC bf16) from NCHW fp32, 64ci x 64sp tile
//  blockIdx.y == N_IMG : wtT[co][k], k = (kh*3+kw)*64 + ci   (from OIHW)
__global__ __launch_bounds__(256) void convert_xw(
    const float* __restrict__ x, const float* __restrict__ w,
    u16* __restrict__ xt, u16* __restrict__ wtT)
{
  if (blockIdx.y == N_IMG) {
    int o = blockIdx.x * 256 + threadIdx.x;
    for (; o < C_OUT * KTOT; o += 49 * 256) {
      int co = o / KTOT;
      int k  = o - co * KTOT;
      int t  = k >> 6;       // kh*3+kw
      int ci = k & 63;
      wtT[o] = f32_bf16_rne(w[co * KTOT + ci * 9 + t]);
    }
    return;
  }

  __shared__ u16 tile[64][68];          // +4 pad: rows stay 8B-aligned, spreads banks
  int n  = blockIdx.y;
  int s0 = blockIdx.x * 64;
  int t  = threadIdx.x;

  // phase 1: float4 coalesced reads, convert, ushort4 LDS writes
  int r = t >> 2;                        // ci row 0..63
  int q = t & 3;                         // 16-float quarter of the 64-sp span
  const float* xp = x + (size_t)n * C_IN * HW_IN + (size_t)r * HW_IN + s0 + q * 16;
  #pragma unroll
  for (int j = 0; j < 4; j++) {
    f32x4 v = *(const f32x4*)(xp + 4 * j);
    u16x4 o4;
    #pragma unroll
    for (int e = 0; e < 4; e++) {
      float f = fminf(fmaxf(v[e], -128.f), 127.f);
      int iv = (int)f;                   // trunc toward zero = astype(int8)
      o4[e] = f32_bf16_rne((float)iv);   // exact: small ints in bf16
    }
    *(u16x4*)&tile[r][q * 16 + 4 * j] = o4;
  }
  __syncthreads();

  // phase 2: transpose out of LDS, ushort8 (16B/lane) coalesced stores
  u16* op = xt + ((size_t)n * HW_IN + s0) * C_IN;
  int g = t & 7;                         // ci group of 8
  int m = t >> 3;                        // 0..31
  #pragma unroll
  for (int k2 = 0; k2 < 2; k2++) {
    int sp = m * 2 + k2;
    u16x8 o8;
    #pragma unroll
    for (int c = 0; c < 8; c++) o8[c] = tile[g * 8 + c][sp];
    *(u16x8*)&op[(size_t)sp * C_IN + g * 8] = o8;
  }
}

// Implicit GEMM, pipelined: block tile 128 spatial x 128 cout, BK=64 (one 3x3 tap),
// 9 chunks, DOUBLE-BUFFERED LDS with ONE barrier per chunk. Chunk k+1's
// global_load_lds DMA is issued right after the barrier and flies during chunk k's
// ds_read+MFMA; the compiler's vmcnt(0) drain inside the NEXT __syncthreads() is
// what completes it -> staging latency hidden instead of serially exposed 9x.
__global__ __launch_bounds__(256) void conv_gemm(
    const u16* __restrict__ xt, const u16* __restrict__ wtT,
    const float* __restrict__ bias, float* __restrict__ y)
{
  __shared__ u16 sP[2][128 * 64];   // pixels  [buf][local spatial row][swizzled 16B groups]
  __shared__ u16 sW[2][128 * 64];   // weights [buf][cout row][swizzled 16B groups]

  int tid  = threadIdx.x;
  int wv   = tid >> 6;
  int lane = tid & 63;
  int ln   = lane & 15;
  int q    = lane >> 4;
  int wy   = wv >> 1;            // cout half
  int wx   = wv & 1;             // spatial half

  int blk_sp0 = blockIdx.x * 128;

  // ---- staging addresses (lane i -> row i>>3, 16B-group i&7, swizzle cg^row8) ----
  int r8 = lane >> 3;            // 0..7
  int cg = lane & 7;             // 16B group
  int scol = (cg ^ r8) * 8;      // u16 offset of swizzled group within 64

  int pix_off[4], wt_off[4];
  #pragma unroll
  for (int j = 0; j < 4; j++) {
    int srow = wv * 32 + j * 8 + r8;           // 0..127
    int p   = blk_sp0 + srow;
    int img = p / SPI;  int rem = p - img * SPI;
    int oh  = rem / OW; int ow  = rem - oh * OW;
    pix_off[j] = (img * HW_IN + oh * W_IN + ow) * C_IN + scol;
    wt_off[j]  = srow * KTOT + scol;
  }

  f32x4 acc[4][4];
  #pragma unroll
  for (int mt = 0; mt < 4; mt++)
    #pragma unroll
    for (int nt = 0; nt < 4; nt++)
      acc[mt][nt] = (f32x4){0.f, 0.f, 0.f, 0.f};

  // frag-read row bases (u16 index); row&7 == ln&7 for the unswizzle
  int wrow[4], prow[4];
  #pragma unroll
  for (int i = 0; i < 4; i++) {
    wrow[i] = (wy * 64 + i * 16 + ln) * 64;
    prow[i] = (wx * 64 + i * 16 + ln) * 64;
  }
  int l7 = ln & 7;
  int lbase = (wv * 32) * 64;    // this wave's staging base (u16)

  // ---- prologue: stage chunk 0 (tap (0,0): xoff = 0, woff = 0) ----
  #pragma unroll
  for (int j = 0; j < 4; j++)
    load16_to_lds(xt + pix_off[j], &sP[0][lbase + j * 8 * 64]);
  #pragma unroll
  for (int j = 0; j < 4; j++)
    load16_to_lds(wtT + wt_off[j], &sW[0][lbase + j * 8 * 64]);

  #pragma unroll
  for (int kc = 0; kc < 9; kc++) {
    const int cur = kc & 1, nxt = cur ^ 1;

    // drains vmcnt(0)+lgkmcnt(0): chunk kc fully landed in LDS for ALL waves,
    // and everyone's reads of buf[nxt] (last iter's cur) are retired.
    __syncthreads();

    if (kc < 8) {   // issue chunk kc+1 DMA; overlaps with the MFMA below
      int kn = kc + 1;
      int kh = kn / 3, kw = kn - kh * 3;
      int xoff = (kh * W_IN + kw) * C_IN;
      #pragma unroll
      for (int j = 0; j < 4; j++)
        load16_to_lds(xt + pix_off[j] + xoff, &sP[nxt][lbase + j * 8 * 64]);
      #pragma unroll
      for (int j = 0; j < 4; j++)
        load16_to_lds(wtT + wt_off[j] + kn * 64, &sW[nxt][lbase + j * 8 * 64]);
    }

    #pragma unroll
    for (int s = 0; s < 2; s++) {
      int pg = ((s * 4 + q) ^ l7) * 8;         // unswizzled physical group
      bf16x8 wf[4], pf[4];
      #pragma unroll
      for (int mt = 0; mt < 4; mt++)
        wf[mt] = *(const bf16x8*)(&sW[cur][0] + wrow[mt] + pg);
      #pragma unroll
      for (int nt = 0; nt < 4; nt++)
        pf[nt] = *(const bf16x8*)(&sP[cur][0] + prow[nt] + pg);
      #pragma unroll
      for (int mt = 0; mt < 4; mt++)
        #pragma unroll
        for (int nt = 0; nt < 4; nt++)
          acc[mt][nt] = __builtin_amdgcn_mfma_f32_16x16x32_bf16(
              wf[mt], pf[nt], acc[mt][nt], 0, 0, 0);
    }
  }

  // epilogue: D row = cout = q*4+reg (within 16-tile), D col = spatial = ln
  #pragma unroll
  for (int nt = 0; nt < 4; nt++) {
    int p   = blk_sp0 + wx * 64 + nt * 16 + ln;
    int img = p / SPI;  int rem = p - img * SPI;
    int oh  = rem / OW; int ow  = rem - oh * OW;
    int obase = img * C_OUT * SPI + oh * OW + ow;
    #pragma unroll
    for (int mt = 0; mt < 4; mt++) {
      int co0 = wy * 64 + mt * 16 + q * 4;
      #pragma unroll
      for (int r = 0; r < 4; r++) {
        int co = co0 + r;
        y[obase + co * SPI] = acc[mt][nt][r] + bias[co];
      }
    }
  }
}

extern "C" void kernel_launch(void* const* d_in, const int* in_sizes, int n_in,
                              void* d_out, int out_size, void* d_ws, size_t ws_size,
                              hipStream_t stream) {
  const float* x    = (const float*)d_in[0];
  const float* w    = (const float*)d_in[1];
  const float* bias = (const float*)d_in[2];
  float* y = (float*)d_out;

  u16* wtT = (u16*)d_ws;
  u16* xt  = (u16*)((char*)d_ws + (size_t)C_OUT * KTOT * sizeof(u16)); // +147456 B

  // y-blocks 0..63: x convert (49 tiles of 64 spatial each); y-block 64: weights
  hipLaunchKernelGGL(convert_xw, dim3(HW_IN / 64, N_IMG + 1), dim3(256), 0, stream,
                     x, w, xt, wtT);
  hipLaunchKernelGGL(conv_gemm, dim3(M_TOTAL / 128), dim3(256), 0, stream,
                     xt, wtT, bias, y);
}

// Round 3
// 167.884 us; speedup vs baseline: 1.1464x; 1.1464x over previous
//
#include <hip/hip_runtime.h>
#include <stdint.h>

typedef unsigned short u16;
typedef __attribute__((ext_vector_type(8))) __bf16 bf16x8;
typedef __attribute__((ext_vector_type(4))) float f32x4;
typedef __attribute__((ext_vector_type(4))) u16 u16x4;
typedef __attribute__((ext_vector_type(8))) u16 u16x8;

#define N_IMG 64
#define C_IN  64
#define HW_IN 3136   // 56*56
#define W_IN  56
#define C_OUT 128
#define OH    54
#define OW    54
#define SPI   2916   // 54*54
#define KTOT  576    // C_IN*9
#define M_TOTAL (N_IMG*SPI)   // 186624 = 128 * 1458
#define NWG   (M_TOTAL/128)   // 1458 conv_gemm blocks

typedef __attribute__((address_space(3))) unsigned int lds_uint;
typedef __attribute__((address_space(1))) unsigned int gbl_uint;

__device__ __forceinline__ void load16_to_lds(const u16* g, u16* l) {
  // lane i of the wave writes LDS base + i*16 bytes; g is per-lane.
  __builtin_amdgcn_global_load_lds((const gbl_uint*)g, (lds_uint*)l, 16, 0, 0);
}

__device__ inline u16 f32_bf16_rne(float f) {
  unsigned u = __float_as_uint(f);
  u = (u + 0x7FFFu + ((u >> 16) & 1u)) >> 16;
  return (u16)u;
}

// Merged converter.
//  blockIdx.y <  N_IMG : xt[n][s][ci] (NHWC bf16) from NCHW fp32, 64ci x 64sp tile
//  blockIdx.y == N_IMG : wtT[co][k], k = (kh*3+kw)*64 + ci   (from OIHW)
__global__ __launch_bounds__(256) void convert_xw(
    const float* __restrict__ x, const float* __restrict__ w,
    u16* __restrict__ xt, u16* __restrict__ wtT)
{
  if (blockIdx.y == N_IMG) {
    int o = blockIdx.x * 256 + threadIdx.x;
    for (; o < C_OUT * KTOT; o += 49 * 256) {
      int co = o / KTOT;
      int k  = o - co * KTOT;
      int t  = k >> 6;       // kh*3+kw
      int ci = k & 63;
      wtT[o] = f32_bf16_rne(w[co * KTOT + ci * 9 + t]);
    }
    return;
  }

  __shared__ u16 tile[64][68];          // +4 pad: rows stay 8B-aligned, spreads banks
  int n  = blockIdx.y;
  int s0 = blockIdx.x * 64;
  int t  = threadIdx.x;

  // phase 1: float4 coalesced reads, convert, ushort4 LDS writes
  int r = t >> 2;                        // ci row 0..63
  int q = t & 3;                         // 16-float quarter of the 64-sp span
  const float* xp = x + (size_t)n * C_IN * HW_IN + (size_t)r * HW_IN + s0 + q * 16;
  #pragma unroll
  for (int j = 0; j < 4; j++) {
    f32x4 v = *(const f32x4*)(xp + 4 * j);
    u16x4 o4;
    #pragma unroll
    for (int e = 0; e < 4; e++) {
      float f = fminf(fmaxf(v[e], -128.f), 127.f);
      int iv = (int)f;                   // trunc toward zero = astype(int8)
      o4[e] = f32_bf16_rne((float)iv);   // exact: small ints in bf16
    }
    *(u16x4*)&tile[r][q * 16 + 4 * j] = o4;
  }
  __syncthreads();

  // phase 2: transpose out of LDS, ushort8 (16B/lane) coalesced stores
  u16* op = xt + ((size_t)n * HW_IN + s0) * C_IN;
  int g = t & 7;                         // ci group of 8
  int m = t >> 3;                        // 0..31
  #pragma unroll
  for (int k2 = 0; k2 < 2; k2++) {
    int sp = m * 2 + k2;
    u16x8 o8;
    #pragma unroll
    for (int c = 0; c < 8; c++) o8[c] = tile[g * 8 + c][sp];
    *(u16x8*)&op[(size_t)sp * C_IN + g * 8] = o8;
  }
}

// Implicit GEMM: block tile 128 spatial x 128 cout, 8 waves (512 threads),
// wave tile 32 cout x 64 spatial -> acc 2x4 (32 VGPR). BK=64 (one 3x3 tap),
// double-buffered LDS, ONE barrier per chunk: chunk kc+1's global_load_lds
// flies during chunk kc's ds_read+MFMA; drained by the NEXT __syncthreads().
// vs round-2: same pipeline but 8 waves/block -> 2 blocks/CU * 8 = 16 waves/CU
// (round-0: ~12, round-2: ~8). TLP is the latency-hider here.
__global__ __launch_bounds__(512, 4) void conv_gemm(
    const u16* __restrict__ xt, const u16* __restrict__ wtT,
    const float* __restrict__ bias, float* __restrict__ y)
{
  __shared__ u16 sP[2][128 * 64];   // pixels  [buf][spatial row][swizzled 16B groups]
  __shared__ u16 sW[2][128 * 64];   // weights [buf][cout row][swizzled 16B groups]

  int tid  = threadIdx.x;
  int wv   = tid >> 6;           // 0..7
  int lane = tid & 63;
  int ln   = lane & 15;
  int q    = lane >> 4;
  int wy   = wv >> 1;            // cout quarter (32 rows)
  int wx   = wv & 1;             // spatial half (64 cols)

  // bijective XCD-aware swizzle (nwg=1458, 1458%8=2 -> m204 variant)
  int orig = blockIdx.x;
  int xcd = orig & 7, j8 = orig >> 3;
  const int qq = NWG / 8, rr = NWG % 8;               // 182, 2
  int wgid = (xcd < rr ? xcd * (qq + 1) : rr * (qq + 1) + (xcd - rr) * qq) + j8;
  int blk_sp0 = wgid * 128;

  // ---- staging addresses (lane i -> row i>>3, 16B-group i&7, swizzle cg^row8) ----
  int r8 = lane >> 3;            // 0..7
  int cg = lane & 7;             // 16B group
  int scol = (cg ^ r8) * 8;      // u16 offset of swizzled group within 64

  int pix_off[2], wt_off[2];
  #pragma unroll
  for (int j = 0; j < 2; j++) {
    int srow = wv * 16 + j * 8 + r8;           // 0..127 across 8 waves
    int p   = blk_sp0 + srow;
    int img = p / SPI;  int rem = p - img * SPI;
    int oh  = rem / OW; int ow  = rem - oh * OW;
    pix_off[j] = (img * HW_IN + oh * W_IN + ow) * C_IN + scol;
    wt_off[j]  = srow * KTOT + scol;
  }

  f32x4 acc[2][4];
  #pragma unroll
  for (int mt = 0; mt < 2; mt++)
    #pragma unroll
    for (int nt = 0; nt < 4; nt++)
      acc[mt][nt] = (f32x4){0.f, 0.f, 0.f, 0.f};

  // frag-read row bases (u16 index); row&7 == ln&7 for the unswizzle
  int wrow[2], prow[4];
  #pragma unroll
  for (int i = 0; i < 2; i++) wrow[i] = (wy * 32 + i * 16 + ln) * 64;
  #pragma unroll
  for (int i = 0; i < 4; i++) prow[i] = (wx * 64 + i * 16 + ln) * 64;
  int l7 = ln & 7;
  int lbase = (wv * 16) * 64;    // this wave's staging base (u16)

  // ---- prologue: stage chunk 0 (tap (0,0)) into buf 0 ----
  #pragma unroll
  for (int j = 0; j < 2; j++)
    load16_to_lds(xt + pix_off[j], &sP[0][lbase + j * 512]);
  #pragma unroll
  for (int j = 0; j < 2; j++)
    load16_to_lds(wtT + wt_off[j], &sW[0][lbase + j * 512]);

  #pragma unroll
  for (int kc = 0; kc < 9; kc++) {
    const int cur = kc & 1, nxt = cur ^ 1;

    // drains vmcnt(0)+lgkmcnt(0): chunk kc fully landed (issued one compute
    // phase ago), and everyone's reads of buf[nxt] (last iter's cur) retired.
    __syncthreads();

    if (kc < 8) {   // issue chunk kc+1 DMA; flies during the MFMA below
      int kn = kc + 1;
      int kh = kn / 3, kw = kn - kh * 3;
      int xoff = (kh * W_IN + kw) * C_IN;
      #pragma unroll
      for (int j = 0; j < 2; j++)
        load16_to_lds(xt + pix_off[j] + xoff, &sP[nxt][lbase + j * 512]);
      #pragma unroll
      for (int j = 0; j < 2; j++)
        load16_to_lds(wtT + wt_off[j] + kn * 64, &sW[nxt][lbase + j * 512]);
    }

    #pragma unroll
    for (int s = 0; s < 2; s++) {
      int pg = ((s * 4 + q) ^ l7) * 8;         // unswizzled physical group
      bf16x8 wf[2], pf[4];
      #pragma unroll
      for (int mt = 0; mt < 2; mt++)
        wf[mt] = *(const bf16x8*)(&sW[cur][0] + wrow[mt] + pg);
      #pragma unroll
      for (int nt = 0; nt < 4; nt++)
        pf[nt] = *(const bf16x8*)(&sP[cur][0] + prow[nt] + pg);
      #pragma unroll
      for (int mt = 0; mt < 2; mt++)
        #pragma unroll
        for (int nt = 0; nt < 4; nt++)
          acc[mt][nt] = __builtin_amdgcn_mfma_f32_16x16x32_bf16(
              wf[mt], pf[nt], acc[mt][nt], 0, 0, 0);
    }
  }

  // epilogue: D row = cout = q*4+reg (within 16-tile), D col = spatial = ln
  #pragma unroll
  for (int nt = 0; nt < 4; nt++) {
    int p   = blk_sp0 + wx * 64 + nt * 16 + ln;
    int img = p / SPI;  int rem = p - img * SPI;
    int oh  = rem / OW; int ow  = rem - oh * OW;
    int obase = img * C_OUT * SPI + oh * OW + ow;
    #pragma unroll
    for (int mt = 0; mt < 2; mt++) {
      int co0 = wy * 32 + mt * 16 + q * 4;
      #pragma unroll
      for (int r = 0; r < 4; r++) {
        int co = co0 + r;
        y[obase + co * SPI] = acc[mt][nt][r] + bias[co];
      }
    }
  }
}

extern "C" void kernel_launch(void* const* d_in, const int* in_sizes, int n_in,
                              void* d_out, int out_size, void* d_ws, size_t ws_size,
                              hipStream_t stream) {
  const float* x    = (const float*)d_in[0];
  const float* w    = (const float*)d_in[1];
  const float* bias = (const float*)d_in[2];
  float* y = (float*)d_out;

  u16* wtT = (u16*)d_ws;
  u16* xt  = (u16*)((char*)d_ws + (size_t)C_OUT * KTOT * sizeof(u16)); // +147456 B

  // y-blocks 0..63: x convert (49 tiles of 64 spatial each); y-block 64: weights
  hipLaunchKernelGGL(convert_xw, dim3(HW_IN / 64, N_IMG + 1), dim3(256), 0, stream,
                     x, w, xt, wtT);
  hipLaunchKernelGGL(conv_gemm, dim3(NWG), dim3(512), 0, stream,
                     xt, wtT, bias, y);
}